// Round 2
// baseline (10871.841 us; speedup 1.0000x reference)
//
#include <hip/hip_runtime.h>
#include <stdint.h>

typedef unsigned short u16;

__device__ __forceinline__ float bf2f(u16 u) {
  union { uint32_t i; float f; } v; v.i = ((uint32_t)u) << 16; return v.f;
}
__device__ __forceinline__ u16 f2bf(float f) {
  union { float f; uint32_t i; } v; v.f = f;
  uint32_t x = v.i;
  return (u16)((x + 0x7FFFu + ((x >> 16) & 1u)) >> 16);
}
__device__ __forceinline__ float sigm(float x) { return 1.f / (1.f + expf(-x)); }

// ---------------- pack / pad kernels ----------------
// f32 src -> bf16 padded dst
__global__ void pad2dbf_k(const float* __restrict__ src, int Rs, int Cs,
                          u16* __restrict__ dst, int Rd, int Cd) {
  int idx = blockIdx.x * 256 + threadIdx.x;
  int tot = Rd * Cd;
  if (idx >= tot) return;
  int r = idx / Cd, c = idx - r * Cd;
  dst[idx] = (r < Rs && c < Cs) ? f2bf(src[(size_t)r * Cs + c]) : (u16)0;
}

__global__ void padbias_k(const float* __restrict__ s1, const float* __restrict__ s2,
                          int Ns, float* __restrict__ dst, int Nd) {
  int i = blockIdx.x * 256 + threadIdx.x;
  if (i >= Nd) return;
  float v = 0.f;
  if (i < Ns) { v = s1[i]; if (s2) v += s2[i]; }
  dst[i] = v;
}

__global__ void zero_k(uint32_t* __restrict__ p, int n) {
  int i = blockIdx.x * 256 + threadIdx.x;
  if (i < n) p[i] = 0u;
}

// ---------------- ax = A_hat @ x[b,t0+tl,:] for chunk; p = tl*4+b ----------------
__global__ void ax_k(const float* __restrict__ x, const float* __restrict__ A,
                     float* __restrict__ axc, int t0) {
  __shared__ float xs[120];
  int p = blockIdx.x, tid = threadIdx.x;
  int tl = p >> 2, b = p & 3;
  if (tid < 120) xs[tid] = x[(size_t)((b * 192) + (t0 + tl)) * 120 + tid];
  __syncthreads();
  if (tid < 120) {
    float s = 0.f;
    #pragma unroll 4
    for (int j = 0; j < 120; j++) s = fmaf(A[tid * 120 + j], xs[j], s);
    axc[p * 120 + tid] = s;
  }
}

// ---------------- g1 = A_hat @ relu(ax ⊗ W1), bf16 out rows p*120+i ----------------
__global__ __launch_bounds__(256) void g1_k(const float* __restrict__ axc,
                                            const float* __restrict__ A,
                                            const float* __restrict__ W1,
                                            u16* __restrict__ g1c) {
  __shared__ float hr[120][64];
  __shared__ float axs[120];
  __shared__ float w1s[64];
  int gt = blockIdx.x, p = blockIdx.y, tid = threadIdx.x;
  if (tid < 120) axs[tid] = axc[p * 120 + tid];
  if (tid < 64) { int g = gt * 64 + tid; w1s[tid] = (g < 500) ? W1[g] : 0.f; }
  __syncthreads();
  for (int e = tid; e < 120 * 64; e += 256) {
    int j = e >> 6, gg = e & 63;
    float v = axs[j] * w1s[gg];
    hr[j][gg] = v > 0.f ? v : 0.f;   // = h1[j][g]
  }
  __syncthreads();
  int gg = tid & 63, iw = tid >> 6;
  int g = gt * 64 + gg;
  for (int pr = iw; pr < 60; pr += 4) {
    int i = pr * 2;
    float a0 = 0.f, a1 = 0.f;
    const float* Ar0 = A + i * 120;
    const float* Ar1 = Ar0 + 120;
    for (int j = 0; j < 120; j++) {
      float h = hr[j][gg];
      a0 = fmaf(Ar0[j], h, a0);
      a1 = fmaf(Ar1[j], h, a1);
    }
    g1c[(size_t)(p * 120 + i) * 512 + g] = f2bf(a0);
    g1c[(size_t)(p * 120 + i + 1) * 512 + g] = f2bf(a1);
  }
}

// ---------------- generic tiled f32-compute GEMM ----------------
// A: bf16 or f32 [M][lda].  B: bf16, NOTRANS [K][ldb] or TRANS [N][ldb(=Kpad)].
// ACT: 0 none, 1 relu, 2 sigmoid.  OUTMAP: final out remap (b,o,l).
template<int BM, int BN, bool ABF16, bool TRANSB, int ACT, bool CBF16, bool OUTMAP>
__global__ __launch_bounds__(256) void gemm_k(
    const void* __restrict__ Av, int lda,
    const u16* __restrict__ B, int ldb,
    const float* __restrict__ bias,
    void* __restrict__ Cv, int ldc, int M, int K) {
  constexpr int TM = BM / 16, TN = BN / 16;
  __shared__ __align__(16) float As[16][BM];
  __shared__ __align__(16) float Bs[16][BN];
  const int tid = threadIdx.x;
  const int tx = tid & 15, ty = tid >> 4;
  const int m0 = blockIdx.y * BM, n0 = blockIdx.x * BN;
  float acc[TM][TN];
  #pragma unroll
  for (int i = 0; i < TM; i++)
    #pragma unroll
    for (int j = 0; j < TN; j++) acc[i][j] = 0.f;

  constexpr int ACPT = BM / 16;      // A elems per thread
  constexpr int ATPR = 16 / ACPT;    // threads per A row
  const int am = tid / ATPR;
  const int ak = (tid % ATPR) * ACPT;
  const int arow = m0 + am;

  constexpr int BCPT = BN / 16;      // B elems per thread
  const int nb_bk = tid >> 4;                 // NOTRANS: k within tile
  const int nb_ns = (tid & 15) * BCPT;        // NOTRANS: n within tile
  constexpr int BTPR = 16 / BCPT;             // TRANS: threads per B row
  const int tb_bn = tid / BTPR;               // TRANS: n within tile
  const int tb_bk = (tid % BTPR) * BCPT;      // TRANS: k within tile

  for (int k0 = 0; k0 < K; k0 += 16) {
    // --- A tile ---
    if constexpr (ABF16) {
      alignas(16) u16 tmp[ACPT];
      if (arow < M) {
        const u16* p = (const u16*)Av + (size_t)arow * lda + k0 + ak;
        if constexpr (ACPT == 8) *(uint4*)tmp = *(const uint4*)p;
        else                     *(uint2*)tmp = *(const uint2*)p;
      } else {
        #pragma unroll
        for (int i = 0; i < ACPT; i++) tmp[i] = 0;
      }
      #pragma unroll
      for (int i = 0; i < ACPT; i++) As[ak + i][am] = bf2f(tmp[i]);
    } else {
      alignas(16) float tmp[ACPT];
      if (arow < M) {
        const float* p = (const float*)Av + (size_t)arow * lda + k0 + ak;
        *(float4*)tmp = *(const float4*)p;
        if constexpr (ACPT == 8) *(float4*)(tmp + 4) = *(const float4*)(p + 4);
      } else {
        #pragma unroll
        for (int i = 0; i < ACPT; i++) tmp[i] = 0.f;
      }
      #pragma unroll
      for (int i = 0; i < ACPT; i++) As[ak + i][am] = tmp[i];
    }
    // --- B tile (bf16) ---
    {
      alignas(16) u16 tb[BCPT];
      if constexpr (!TRANSB) {
        const u16* p = B + (size_t)(k0 + nb_bk) * ldb + n0 + nb_ns;
        if constexpr (BCPT == 8) *(uint4*)tb = *(const uint4*)p;
        else                     *(uint2*)tb = *(const uint2*)p;
        #pragma unroll
        for (int c = 0; c < BCPT; c++) Bs[nb_bk][nb_ns + c] = bf2f(tb[c]);
      } else {
        const u16* p = B + (size_t)(n0 + tb_bn) * ldb + k0 + tb_bk;
        if constexpr (BCPT == 8) *(uint4*)tb = *(const uint4*)p;
        else                     *(uint2*)tb = *(const uint2*)p;
        #pragma unroll
        for (int c = 0; c < BCPT; c++) Bs[tb_bk + c][tb_bn] = bf2f(tb[c]);
      }
    }
    __syncthreads();
    #pragma unroll
    for (int k = 0; k < 16; k++) {
      float a[TM], b[TN];
      #pragma unroll
      for (int i = 0; i < TM; i += 4) *(float4*)(a + i) = *(const float4*)&As[k][ty * TM + i];
      #pragma unroll
      for (int j = 0; j < TN; j += 4) *(float4*)(b + j) = *(const float4*)&Bs[k][tx * TN + j];
      #pragma unroll
      for (int i = 0; i < TM; i++)
        #pragma unroll
        for (int j = 0; j < TN; j++)
          acc[i][j] = fmaf(a[i], b[j], acc[i][j]);
    }
    __syncthreads();
  }

  #pragma unroll
  for (int i = 0; i < TM; i++) {
    int m = m0 + ty * TM + i;
    if (m >= M) continue;
    #pragma unroll
    for (int j = 0; j < TN; j++) {
      int n = n0 + tx * TN + j;
      float v = acc[i][j];
      if (bias) v += bias[n];
      if constexpr (ACT == 1) v = v > 0.f ? v : 0.f;
      if constexpr (ACT == 2) v = sigm(v);
      if constexpr (OUTMAP) {
        if (n < 24) {
          int b = m / 120, l = m - (m / 120) * 120;
          ((float*)Cv)[(size_t)(b * 24 + n) * 120 + l] = v;
        }
      } else if constexpr (CBF16) {
        ((u16*)Cv)[(size_t)m * ldc + n] = f2bf(v);
      } else {
        ((float*)Cv)[(size_t)m * ldc + n] = v;
      }
    }
  }
}

// ---------------- LSTM elementwise cell (f32 h/c) ----------------
__global__ void cell_k(const u16* __restrict__ gt, const float* __restrict__ r,
                       float* __restrict__ c, float* __restrict__ hout) {
  int idx = blockIdx.x * 256 + threadIdx.x;
  if (idx >= 480 * 500) return;
  int n = idx / 500, j = idx - n * 500;
  const u16* g = gt + (size_t)n * 2048;
  const float* rr = r + (size_t)n * 2048;
  float gi = bf2f(g[j]) + rr[j];
  float gf = bf2f(g[500 + j]) + rr[500 + j];
  float gc = bf2f(g[1000 + j]) + rr[1000 + j];
  float go = bf2f(g[1500 + j]) + rr[1500 + j];
  float cn = sigm(gf) * c[n * 512 + j] + sigm(gi) * tanhf(gc);
  c[n * 512 + j] = cn;
  hout[(size_t)n * 512 + j] = sigm(go) * tanhf(cn);
}

// ---------------- launch ----------------
extern "C" void kernel_launch(void* const* d_in, const int* in_sizes, int n_in,
                              void* d_out, int out_size, void* d_ws, size_t ws_size,
                              hipStream_t stream) {
  const float* x   = (const float*)d_in[0];
  const float* Ah  = (const float*)d_in[1];
  const float* W1  = (const float*)d_in[2];
  const float* W2  = (const float*)d_in[3];
  const float* Wih = (const float*)d_in[4];
  const float* Whh = (const float*)d_in[5];
  const float* bih = (const float*)d_in[6];
  const float* bhh = (const float*)d_in[7];
  const float* Wh1 = (const float*)d_in[8];
  const float* bh1 = (const float*)d_in[9];
  const float* Wh2 = (const float*)d_in[10];
  const float* bh2 = (const float*)d_in[11];
  const float* Wh3 = (const float*)d_in[12];
  const float* bh3 = (const float*)d_in[13];
  const float* Wh4 = (const float*)d_in[14];
  const float* bh4 = (const float*)d_in[15];
  (void)in_sizes; (void)n_in; (void)out_size;

  char* ws = (char*)d_ws;
  size_t off = 0;
  auto alloc = [&](size_t bytes) -> char* {
    char* p = ws + off;
    off += (bytes + 1023) & ~(size_t)1023;
    return p;
  };

  u16 *gatesc, *g1c, *h2c, *W2p, *Wihp, *Whhp, *Wh1p, *Wh2p, *Wh3p, *Wh4p, *z1, *z2, *z3;
  float *axc, *biasg, *bh1p, *bh2p, *bh3p, *bh4p, *hA, *hB, *cbuf, *rbuf;

  auto doplan = [&](int tc) {
    off = 0;
    gatesc = (u16*)alloc((size_t)tc * 480 * 2048 * 2);
    g1c    = (u16*)alloc((size_t)tc * 480 * 512 * 2);
    h2c    = (u16*)alloc((size_t)tc * 480 * 512 * 2);
    axc    = (float*)alloc((size_t)tc * 4 * 120 * 4);
    W2p    = (u16*)alloc((size_t)512 * 512 * 2);
    Wihp   = (u16*)alloc((size_t)2048 * 512 * 2);
    Whhp   = (u16*)alloc((size_t)2048 * 512 * 2);
    Wh1p   = (u16*)alloc((size_t)512 * 3072 * 2);
    Wh2p   = (u16*)alloc((size_t)3072 * 1024 * 2);
    Wh3p   = (u16*)alloc((size_t)1024 * 3072 * 2);
    Wh4p   = (u16*)alloc((size_t)3072 * 128 * 2);
    biasg  = (float*)alloc(2048 * 4);
    bh1p   = (float*)alloc(3072 * 4);
    bh2p   = (float*)alloc(1024 * 4);
    bh3p   = (float*)alloc(3072 * 4);
    bh4p   = (float*)alloc(128 * 4);
    hA     = (float*)alloc((size_t)480 * 512 * 4);   // must stay adjacent:
    hB     = (float*)alloc((size_t)480 * 512 * 4);   // hA,hB,cbuf zeroed together
    cbuf   = (float*)alloc((size_t)480 * 512 * 4);
    rbuf   = (float*)alloc((size_t)480 * 2048 * 4);
    z1     = (u16*)alloc((size_t)480 * 3072 * 2);
    z2     = (u16*)alloc((size_t)480 * 1024 * 2);
    z3     = (u16*)alloc((size_t)480 * 3072 * 2);
  };
  int TC = 16;
  doplan(TC);
  if (off > ws_size) { TC = 8;  doplan(TC); }
  if (off > ws_size) { TC = 4;  doplan(TC); }
  // TC=4 needs ~44 MB; below that nothing fits — proceed regardless.

  // ---- weight packing (bf16, zero-padded) ----
  pad2dbf_k<<<(512 * 512 + 255) / 256, 256, 0, stream>>>(W2, 500, 500, W2p, 512, 512);
  pad2dbf_k<<<(2048 * 512 + 255) / 256, 256, 0, stream>>>(Wih, 2000, 500, Wihp, 2048, 512);
  pad2dbf_k<<<(2048 * 512 + 255) / 256, 256, 0, stream>>>(Whh, 2000, 500, Whhp, 2048, 512);
  pad2dbf_k<<<(512 * 3072 + 255) / 256, 256, 0, stream>>>(Wh1, 500, 3000, Wh1p, 512, 3072);
  pad2dbf_k<<<(3072 * 1024 + 255) / 256, 256, 0, stream>>>(Wh2, 3000, 1000, Wh2p, 3072, 1024);
  pad2dbf_k<<<(1024 * 3072 + 255) / 256, 256, 0, stream>>>(Wh3, 1000, 3000, Wh3p, 1024, 3072);
  pad2dbf_k<<<(3072 * 128 + 255) / 256, 256, 0, stream>>>(Wh4, 3000, 24, Wh4p, 3072, 128);
  padbias_k<<<8, 256, 0, stream>>>(bih, bhh, 2000, biasg, 2048);
  padbias_k<<<12, 256, 0, stream>>>(bh1, nullptr, 3000, bh1p, 3072);
  padbias_k<<<4, 256, 0, stream>>>(bh2, nullptr, 1000, bh2p, 1024);
  padbias_k<<<12, 256, 0, stream>>>(bh3, nullptr, 3000, bh3p, 3072);
  padbias_k<<<1, 256, 0, stream>>>(bh4, nullptr, 24, bh4p, 128);

  // zero h double-buffer + c (contiguous: 3 * 983040 B)
  zero_k<<<2880, 256, 0, stream>>>((uint32_t*)hA, 737280);

  float* hc = hA; float* hn = hB;
  const int NCH = 192 / TC;
  for (int ci = 0; ci < NCH; ci++) {
    int t0 = ci * TC;
    int M = TC * 480;
    ax_k<<<TC * 4, 128, 0, stream>>>(x, Ah, axc, t0);
    g1_k<<<dim3(8, TC * 4), 256, 0, stream>>>(axc, Ah, W1, g1c);
    // h2 = relu(g1 @ W2p)   M x 512, K=512
    gemm_k<128, 128, true, false, 1, true, false><<<dim3(4, M / 128), 256, 0, stream>>>(
        g1c, 512, W2p, 512, nullptr, h2c, 512, M, 512);
    // gates = h2 @ Wih^T + (b_ih+b_hh)   M x 2048, K=512
    gemm_k<128, 128, true, true, 0, true, false><<<dim3(16, M / 128), 256, 0, stream>>>(
        h2c, 512, Wihp, 512, biasg, gatesc, 2048, M, 512);
    // LSTM steps consuming this chunk
    for (int tl = 0; tl < TC; tl++) {
      gemm_k<64, 64, false, true, 0, false, false><<<dim3(32, 8), 256, 0, stream>>>(
          hc, 512, Whhp, 512, nullptr, rbuf, 2048, 480, 512);
      cell_k<<<938, 256, 0, stream>>>(gatesc + (size_t)tl * 480 * 2048, rbuf, cbuf, hn);
      float* tsw = hc; hc = hn; hn = tsw;
    }
  }

  // ---- MLP head (hc = h_last, f32) ----
  gemm_k<64, 64, false, false, 1, true, false><<<dim3(48, 8), 256, 0, stream>>>(
      hc, 512, Wh1p, 3072, bh1p, z1, 3072, 480, 512);
  gemm_k<64, 64, true, false, 1, true, false><<<dim3(16, 8), 256, 0, stream>>>(
      z1, 3072, Wh2p, 1024, bh2p, z2, 1024, 480, 3072);
  gemm_k<64, 64, true, false, 1, true, false><<<dim3(48, 8), 256, 0, stream>>>(
      z2, 1024, Wh3p, 3072, bh3p, z3, 3072, 480, 1024);
  gemm_k<64, 64, true, false, 2, false, true><<<dim3(2, 8), 256, 0, stream>>>(
      z3, 3072, Wh4p, 128, bh4p, d_out, 0, 480, 3072);
}

// Round 3
// 4715.145 us; speedup vs baseline: 2.3057x; 2.3057x over previous
//
#include <hip/hip_runtime.h>
#include <stdint.h>

typedef unsigned short u16;
typedef short bf16x8 __attribute__((ext_vector_type(8)));
typedef float f32x4 __attribute__((ext_vector_type(4)));

__device__ __forceinline__ float bf2f(u16 u) {
  union { uint32_t i; float f; } v; v.i = ((uint32_t)u) << 16; return v.f;
}
__device__ __forceinline__ u16 f2bf(float f) {
  union { float f; uint32_t i; } v; v.f = f;
  uint32_t x = v.i;
  return (u16)((x + 0x7FFFu + ((x >> 16) & 1u)) >> 16);
}
__device__ __forceinline__ float sigm(float x) { return 1.f / (1.f + expf(-x)); }

// ---------------- packing ----------------
// Wih/Whh [2000][500] f32 -> [2048][512] bf16, rows interleaved c = j*4+g
__global__ void packgate_k(const float* __restrict__ src, u16* __restrict__ dst) {
  int idx = blockIdx.x * 256 + threadIdx.x;
  if (idx >= 2048 * 512) return;
  int crow = idx >> 9, k = idx & 511;
  int j = crow >> 2, g = crow & 3;
  u16 v = 0;
  if (j < 500 && k < 500) v = f2bf(src[(size_t)(g * 500 + j) * 500 + k]);
  dst[idx] = v;
}

__global__ void gatebias_k(const float* __restrict__ bih, const float* __restrict__ bhh,
                           float* __restrict__ dst) {
  int c = blockIdx.x * 256 + threadIdx.x;
  if (c >= 2048) return;
  int j = c >> 2, g = c & 3;
  dst[c] = (j < 500) ? bih[g * 500 + j] + bhh[g * 500 + j] : 0.f;
}

// src f32 [Ks][Ns] -> dst bf16 [Nd][Kd] (transposed, zero-padded)
__global__ void packT_k(const float* __restrict__ src, int Ks, int Ns,
                        u16* __restrict__ dst, int Nd, int Kd) {
  int idx = blockIdx.x * 256 + threadIdx.x;
  if (idx >= Nd * Kd) return;
  int n = idx / Kd, k = idx - n * Kd;
  dst[idx] = (n < Ns && k < Ks) ? f2bf(src[(size_t)k * Ns + n]) : (u16)0;
}

__global__ void padbias_k(const float* __restrict__ s, int Ns, float* __restrict__ dst, int Nd) {
  int i = blockIdx.x * 256 + threadIdx.x;
  if (i >= Nd) return;
  dst[i] = (i < Ns) ? s[i] : 0.f;
}

__global__ void zero_k(uint32_t* __restrict__ p, int n) {
  int i = blockIdx.x * 256 + threadIdx.x;
  if (i < n) p[i] = 0u;
}

// ---------------- c1 = W2^T W1+, c2 = W2^T W1- ----------------
__global__ void c12_k(const float* __restrict__ W1, const float* __restrict__ W2,
                      float* __restrict__ c1, float* __restrict__ c2) {
  int f = blockIdx.x * 256 + threadIdx.x;
  if (f >= 512) return;
  float s1 = 0.f, s2 = 0.f;
  if (f < 500) {
    for (int g = 0; g < 500; g++) {
      float w = W1[g];
      float v = W2[(size_t)g * 500 + f];
      s1 = fmaf(fmaxf(w, 0.f), v, s1);
      s2 = fmaf(fminf(w, 0.f), v, s2);
    }
  }
  c1[f] = s1; c2[f] = s2;
}

// ---------------- p = A@(A@x)+, q = A@(A@x)-  (rank-2 GCN front) ----------------
__global__ void pq_k(const float* __restrict__ x, const float* __restrict__ A,
                     float* __restrict__ p, float* __restrict__ q) {
  __shared__ float xs[120], axp[120], axm[120];
  int bt = blockIdx.x, tid = threadIdx.x;
  int t = bt >> 2, b = bt & 3;
  if (tid < 120) xs[tid] = x[(size_t)(b * 192 + t) * 120 + tid];
  __syncthreads();
  if (tid < 120) {
    const float* Ar = A + tid * 120;
    float s = 0.f;
    for (int j = 0; j < 120; j++) s = fmaf(Ar[j], xs[j], s);
    axp[tid] = fmaxf(s, 0.f);
    axm[tid] = fminf(s, 0.f);
  }
  __syncthreads();
  if (tid < 120) {
    const float* Ar = A + tid * 120;
    float sp = 0.f, sm = 0.f;
    for (int j = 0; j < 120; j++) { float a = Ar[j]; sp = fmaf(a, axp[j], sp); sm = fmaf(a, axm[j], sm); }
    int o = t * 480 + b * 120 + tid;
    p[o] = sp; q[o] = sm;
  }
}

// ---------------- h2 materialization: h2 = relu(p*c1 + q*c2), bf16 ----------------
__global__ void h2mat_k(const float* __restrict__ p, const float* __restrict__ q,
                        const float* __restrict__ c1, const float* __restrict__ c2,
                        u16* __restrict__ h2c, int R0) {
  int row = blockIdx.x * 4 + (threadIdx.x >> 6);
  int go = (threadIdx.x & 63) * 8;
  float pv = p[R0 + row], qv = q[R0 + row];
  alignas(16) u16 o[8];
  #pragma unroll
  for (int i = 0; i < 8; i++) {
    float v = pv * c1[go + i] + qv * c2[go + i];
    o[i] = f2bf(fmaxf(v, 0.f));
  }
  *(uint4*)&h2c[(size_t)row * 512 + go] = *(const uint4*)o;
}

// ---------------- MFMA GEMM: C = act(A @ B^T + bias) ----------------
// A bf16 [M][lda], B bf16 [N][ldb] (N-major, K-contiguous). 4 waves.
// Wave grid WM x WN, wave tile (FM*16) x (FN*16).
// ACT: 0 none, 1 relu, 2 sigmoid. OUTK: 0 f32, 1 bf16, 2 final-output remap.
template<int BM, int BN, int WM, int WN, int ACT, int OUTK>
__global__ __launch_bounds__(256) void mgemm_k(
    const u16* __restrict__ A, int lda,
    const u16* __restrict__ B, int ldb,
    const float* __restrict__ bias,
    void* __restrict__ Cv, int ldc, int M, int K) {
  constexpr int FM = BM / (WM * 16), FN = BN / (WN * 16);
  const int tid = threadIdx.x;
  const int wid = tid >> 6, lane = tid & 63;
  const int lr = lane & 15, lko = (lane >> 4) << 3;
  const int m0 = blockIdx.y * BM + (wid % WM) * (FM * 16);
  const int n0 = blockIdx.x * BN + (wid / WM) * (FN * 16);

  f32x4 acc[FM][FN];
  #pragma unroll
  for (int i = 0; i < FM; i++)
    #pragma unroll
    for (int j = 0; j < FN; j++) acc[i][j] = (f32x4){0.f, 0.f, 0.f, 0.f};

  const u16* Ap[FM];
  const u16* Bp[FN];
  #pragma unroll
  for (int i = 0; i < FM; i++) {
    int r = m0 + i * 16 + lr;
    if (r > M - 1) r = M - 1;   // clamp (garbage rows never written out)
    Ap[i] = A + (size_t)r * lda + lko;
  }
  #pragma unroll
  for (int j = 0; j < FN; j++) Bp[j] = B + (size_t)(n0 + j * 16 + lr) * ldb + lko;

  #pragma unroll 2
  for (int k0 = 0; k0 < K; k0 += 32) {
    bf16x8 av[FM], bv[FN];
    #pragma unroll
    for (int i = 0; i < FM; i++) av[i] = *(const bf16x8*)(Ap[i] + k0);
    #pragma unroll
    for (int j = 0; j < FN; j++) bv[j] = *(const bf16x8*)(Bp[j] + k0);
    #pragma unroll
    for (int i = 0; i < FM; i++)
      #pragma unroll
      for (int j = 0; j < FN; j++)
        acc[i][j] = __builtin_amdgcn_mfma_f32_16x16x32_bf16(av[i], bv[j], acc[i][j], 0, 0, 0);
  }

  const int rbase = (lane >> 4) << 2;
  #pragma unroll
  for (int i = 0; i < FM; i++) {
    #pragma unroll
    for (int r = 0; r < 4; r++) {
      int m = m0 + i * 16 + rbase + r;
      if (m >= M) continue;
      #pragma unroll
      for (int j = 0; j < FN; j++) {
        int n = n0 + j * 16 + lr;
        float v = acc[i][j][r];
        if (bias) v += bias[n];
        if constexpr (ACT == 1) v = fmaxf(v, 0.f);
        if constexpr (ACT == 2) v = sigm(v);
        if constexpr (OUTK == 0) {
          ((float*)Cv)[(size_t)m * ldc + n] = v;
        } else if constexpr (OUTK == 1) {
          ((u16*)Cv)[(size_t)m * ldc + n] = f2bf(v);
        } else {
          if (n < 24) {
            int bb = m / 120, ll = m - bb * 120;
            ((float*)Cv)[(size_t)(bb * 24 + n) * 120 + ll] = v;
          }
        }
      }
    }
  }
}

// ---------------- fused LSTM step: r = h @ Whh^T (MFMA), then cell ----------------
// Whh interleaved [2048][512]; gates slice [480][2048] bf16 (interleaved cols);
// c f32 [480][512]; h bf16 [480][512]. Grid (8, 15), 256 thr.
__global__ __launch_bounds__(256) void lstm_step_k(
    const u16* __restrict__ h_in, const u16* __restrict__ Whh,
    const u16* __restrict__ gates, float* __restrict__ c, u16* __restrict__ h_out) {
  __shared__ float rs[32][260];
  const int tid = threadIdx.x, wid = tid >> 6, lane = tid & 63;
  const int lr = lane & 15, lko = (lane >> 4) << 3;
  const int m0 = blockIdx.y * 32;
  const int nb = blockIdx.x * 256;
  const int n0 = nb + wid * 64;

  f32x4 acc[2][4];
  #pragma unroll
  for (int i = 0; i < 2; i++)
    #pragma unroll
    for (int j = 0; j < 4; j++) acc[i][j] = (f32x4){0.f, 0.f, 0.f, 0.f};

  const u16* Ap[2];
  const u16* Bp[4];
  #pragma unroll
  for (int i = 0; i < 2; i++) Ap[i] = h_in + (size_t)(m0 + i * 16 + lr) * 512 + lko;
  #pragma unroll
  for (int j = 0; j < 4; j++) Bp[j] = Whh + (size_t)(n0 + j * 16 + lr) * 512 + lko;

  #pragma unroll 2
  for (int k0 = 0; k0 < 512; k0 += 32) {
    bf16x8 av[2], bv[4];
    #pragma unroll
    for (int i = 0; i < 2; i++) av[i] = *(const bf16x8*)(Ap[i] + k0);
    #pragma unroll
    for (int j = 0; j < 4; j++) bv[j] = *(const bf16x8*)(Bp[j] + k0);
    #pragma unroll
    for (int i = 0; i < 2; i++)
      #pragma unroll
      for (int j = 0; j < 4; j++)
        acc[i][j] = __builtin_amdgcn_mfma_f32_16x16x32_bf16(av[i], bv[j], acc[i][j], 0, 0, 0);
  }

  const int rbase = (lane >> 4) << 2;
  #pragma unroll
  for (int i = 0; i < 2; i++)
    #pragma unroll
    for (int j = 0; j < 4; j++)
      #pragma unroll
      for (int r = 0; r < 4; r++)
        rs[i * 16 + rbase + r][wid * 64 + j * 16 + lr] = acc[i][j][r];
  __syncthreads();

  #pragma unroll
  for (int it = 0; it < 8; it++) {
    int qq = tid + it * 256;
    int ml = qq >> 6, jq = qq & 63;
    int m = m0 + ml;
    int jg = (nb >> 2) + jq;
    float4 rv = *(const float4*)&rs[ml][jq * 4];
    const u16* g = gates + (size_t)m * 2048 + nb + jq * 4;
    float gi = bf2f(g[0]) + rv.x;
    float gf = bf2f(g[1]) + rv.y;
    float gg = bf2f(g[2]) + rv.z;
    float go = bf2f(g[3]) + rv.w;
    size_t ci = (size_t)m * 512 + jg;
    float cn = sigm(gf) * c[ci] + sigm(gi) * tanhf(gg);
    c[ci] = cn;
    h_out[ci] = f2bf(sigm(go) * tanhf(cn));
  }
}

// ---------------- launch ----------------
extern "C" void kernel_launch(void* const* d_in, const int* in_sizes, int n_in,
                              void* d_out, int out_size, void* d_ws, size_t ws_size,
                              hipStream_t stream) {
  const float* x   = (const float*)d_in[0];
  const float* Ah  = (const float*)d_in[1];
  const float* W1  = (const float*)d_in[2];
  const float* W2  = (const float*)d_in[3];
  const float* Wih = (const float*)d_in[4];
  const float* Whh = (const float*)d_in[5];
  const float* bih = (const float*)d_in[6];
  const float* bhh = (const float*)d_in[7];
  const float* Wh1 = (const float*)d_in[8];
  const float* bh1 = (const float*)d_in[9];
  const float* Wh2 = (const float*)d_in[10];
  const float* bh2 = (const float*)d_in[11];
  const float* Wh3 = (const float*)d_in[12];
  const float* bh3 = (const float*)d_in[13];
  const float* Wh4 = (const float*)d_in[14];
  const float* bh4 = (const float*)d_in[15];
  (void)in_sizes; (void)n_in; (void)out_size;

  char* ws = (char*)d_ws;
  size_t off = 0;
  auto alloc = [&](size_t bytes) -> char* {
    char* p = ws + off;
    off += (bytes + 1023) & ~(size_t)1023;
    return p;
  };

  u16 *gatesc, *h2c, *Wihp, *Whhp, *Wh1p, *Wh2p, *Wh3p, *Wh4p, *hA, *hB, *z1, *z2, *z3;
  float *pbuf, *qbuf, *c1, *c2, *biasg, *bh1p, *bh2p, *bh3p, *bh4p, *cbuf;

  auto doplan = [&](int tc) {
    off = 0;
    gatesc = (u16*)alloc((size_t)tc * 480 * 2048 * 2);
    h2c    = (u16*)alloc((size_t)tc * 480 * 512 * 2);
    pbuf   = (float*)alloc((size_t)192 * 480 * 4);
    qbuf   = (float*)alloc((size_t)192 * 480 * 4);
    c1     = (float*)alloc(512 * 4);
    c2     = (float*)alloc(512 * 4);
    Wihp   = (u16*)alloc((size_t)2048 * 512 * 2);
    Whhp   = (u16*)alloc((size_t)2048 * 512 * 2);
    Wh1p   = (u16*)alloc((size_t)3072 * 512 * 2);
    Wh2p   = (u16*)alloc((size_t)1024 * 3072 * 2);
    Wh3p   = (u16*)alloc((size_t)3072 * 1024 * 2);
    Wh4p   = (u16*)alloc((size_t)128 * 3072 * 2);
    biasg  = (float*)alloc(2048 * 4);
    bh1p   = (float*)alloc(3072 * 4);
    bh2p   = (float*)alloc(1024 * 4);
    bh3p   = (float*)alloc(3072 * 4);
    bh4p   = (float*)alloc(128 * 4);
    hA     = (u16*)alloc((size_t)480 * 512 * 2);   // hA + cbuf contiguous (zeroed together)
    cbuf   = (float*)alloc((size_t)480 * 512 * 4);
    hB     = (u16*)alloc((size_t)480 * 512 * 2);
    z1     = (u16*)alloc((size_t)480 * 3072 * 2);
    z2     = (u16*)alloc((size_t)480 * 1024 * 2);
    z3     = (u16*)alloc((size_t)480 * 3072 * 2);
  };
  int TC = 16;
  doplan(TC);
  if (off > ws_size) { TC = 8; doplan(TC); }
  if (off > ws_size) { TC = 4; doplan(TC); }

  // ---- weight packing ----
  packgate_k<<<4096, 256, 0, stream>>>(Wih, Wihp);
  packgate_k<<<4096, 256, 0, stream>>>(Whh, Whhp);
  gatebias_k<<<8, 256, 0, stream>>>(bih, bhh, biasg);
  packT_k<<<6144, 256, 0, stream>>>(Wh1, 500, 3000, Wh1p, 3072, 512);
  packT_k<<<12288, 256, 0, stream>>>(Wh2, 3000, 1000, Wh2p, 1024, 3072);
  packT_k<<<12288, 256, 0, stream>>>(Wh3, 1000, 3000, Wh3p, 3072, 1024);
  packT_k<<<1536, 256, 0, stream>>>(Wh4, 3000, 24, Wh4p, 128, 3072);
  padbias_k<<<12, 256, 0, stream>>>(bh1, 3000, bh1p, 3072);
  padbias_k<<<4, 256, 0, stream>>>(bh2, 1000, bh2p, 1024);
  padbias_k<<<12, 256, 0, stream>>>(bh3, 3000, bh3p, 3072);
  padbias_k<<<1, 256, 0, stream>>>(bh4, 24, bh4p, 128);

  // ---- GCN rank-2 front ----
  c12_k<<<2, 256, 0, stream>>>(W1, W2, c1, c2);
  pq_k<<<768, 128, 0, stream>>>(x, Ah, pbuf, qbuf);

  // zero h0 (bf16) + c0 (f32): contiguous 491520 + 983040 bytes
  zero_k<<<1440, 256, 0, stream>>>((uint32_t*)hA, 368640);

  u16* hc = hA; u16* hn = hB;
  const int NCH = 192 / TC;
  for (int ci = 0; ci < NCH; ci++) {
    int R0 = ci * TC * 480;
    int M = TC * 480;
    h2mat_k<<<M / 4, 256, 0, stream>>>(pbuf, qbuf, c1, c2, h2c, R0);
    // gates = h2 @ Wih'^T + biasg   (interleaved cols), M x 2048, K=512
    mgemm_k<128, 128, 2, 2, 0, 1><<<dim3(16, M / 128), 256, 0, stream>>>(
        h2c, 512, Wihp, 512, biasg, gatesc, 2048, M, 512);
    for (int tl = 0; tl < TC; tl++) {
      lstm_step_k<<<dim3(8, 15), 256, 0, stream>>>(
          hc, Whhp, gatesc + (size_t)tl * 480 * 2048, cbuf, hn);
      u16* t_ = hc; hc = hn; hn = t_;
    }
  }

  // ---- MLP head ----
  mgemm_k<32, 256, 1, 4, 1, 1><<<dim3(12, 15), 256, 0, stream>>>(
      hc, 512, Wh1p, 512, bh1p, z1, 3072, 480, 512);
  mgemm_k<32, 256, 1, 4, 1, 1><<<dim3(4, 15), 256, 0, stream>>>(
      z1, 3072, Wh2p, 3072, bh2p, z2, 1024, 480, 3072);
  mgemm_k<32, 256, 1, 4, 1, 1><<<dim3(12, 15), 256, 0, stream>>>(
      z2, 1024, Wh3p, 1024, bh3p, z3, 3072, 480, 1024);
  mgemm_k<32, 128, 1, 4, 2, 2><<<dim3(1, 15), 256, 0, stream>>>(
      z3, 3072, Wh4p, 3072, bh4p, d_out, 0, 480, 3072);
}